// Round 1
// baseline (300.347 us; speedup 1.0000x reference)
//
#include <hip/hip_runtime.h>
#include <hip/hip_bf16.h>

typedef float f32x4 __attribute__((ext_vector_type(4)));
typedef short short8 __attribute__((ext_vector_type(8)));
typedef __bf16 bf16x8 __attribute__((ext_vector_type(8)));

#define N_TOT 16384
#define FEATS 256
#define BM 256
#define BK 32
#define KSPLIT 4
#define LDA (BK + 8)   // pad: stride 40 bf16 = 80B, keeps 16B alignment for b128

static __device__ __forceinline__ ushort f2bf(float f) {
  union { __hip_bfloat16 b; ushort u; } cv;
  cv.b = __float2bfloat16(f);
  return cv.u;
}
static __device__ __forceinline__ float bf2f(ushort u) {
  union { unsigned int i; float f; } c;
  c.i = ((unsigned int)u) << 16;
  return c.f;
}

// ---- K0a: transpose+convert features [16384][256] f32 -> fT [256][16384] bf16
__global__ __launch_bounds__(256) void k_transpose(const float* __restrict__ feat,
                                                   ushort* __restrict__ fT) {
  __shared__ float tile[64][65];
  const int tx = threadIdx.x & 63, ty = threadIdx.x >> 6;
  const int k0 = blockIdx.x * 64, n0 = blockIdx.y * 64;
#pragma unroll
  for (int j = 0; j < 64; j += 4)
    tile[ty + j][tx] = feat[(size_t)(k0 + ty + j) * FEATS + n0 + tx];
  __syncthreads();
#pragma unroll
  for (int j = 0; j < 64; j += 4)
    fT[(size_t)(n0 + ty + j) * N_TOT + k0 + tx] = f2bf(tile[tx][ty + j]);
}

// ---- K0b: convert W [256][256] f32 -> bf16 (layout [o][i] kept: that IS B^T layout)
__global__ __launch_bounds__(256) void k_convw(const float* __restrict__ W,
                                               ushort* __restrict__ Wb) {
  int i = (blockIdx.x * 256 + threadIdx.x) * 4;
  float4 v = *(const float4*)(W + i);
  ushort4 h = { f2bf(v.x), f2bf(v.y), f2bf(v.z), f2bf(v.w) };
  *(ushort4*)(Wb + i) = h;
}

// ---- K1: partials[kb] = graph[:, kchunk] @ features[kchunk, :]   (bf16 MFMA)
// grid (64 row-tiles, KSPLIT), 512 threads = 8 waves (2M x 4N), wave tile 128x64
__global__ __launch_bounds__(512) void k_gemm1(const float* __restrict__ graph,
                                               const ushort* __restrict__ fT,
                                               ushort* __restrict__ parts) {
  __shared__ ushort Alds[2][BM][LDA];     // 40 KiB
  __shared__ ushort Blds[2][FEATS][LDA];  // 40 KiB
  const int tid = threadIdx.x;
  const int lane = tid & 63, w = tid >> 6;
  const int wm = w >> 2, wn = w & 3;
  const size_t m0 = (size_t)blockIdx.x * BM;
  const int kbase = blockIdx.y * (N_TOT / KSPLIT);
  const int nsteps = (N_TOT / KSPLIT) / BK;  // 128

  f32x4 acc[8][4] = {};

  auto stage = [&](int bf, int kk) {
    // A tile: 256 rows x 32 k, fp32 -> bf16. Lanes 0-7 cover one row's 32 floats
    // (128B contiguous) -> perfectly coalesced.
#pragma unroll
    for (int i = 0; i < 4; ++i) {
      const int row = i * 64 + (tid >> 3);
      const int kq = (tid & 7) << 2;
      const float4 v = *(const float4*)(graph + (size_t)(m0 + row) * N_TOT + kk + kq);
      ushort4 h = { f2bf(v.x), f2bf(v.y), f2bf(v.z), f2bf(v.w) };
      *(ushort4*)&Alds[bf][row][kq] = h;
    }
    // B tile: fT is [n][k] bf16, contiguous in k -> 16B loads, 16B LDS writes
    {
      const int n = tid >> 1;
      const int kq = (tid & 1) << 4;
      const short8 v0 = *(const short8*)(fT + (size_t)n * N_TOT + kk + kq);
      const short8 v1 = *(const short8*)(fT + (size_t)n * N_TOT + kk + kq + 8);
      *(short8*)&Blds[bf][n][kq] = v0;
      *(short8*)&Blds[bf][n][kq + 8] = v1;
    }
  };

  stage(0, kbase);
  __syncthreads();

  for (int step = 0; step < nsteps; ++step) {
    const int cur = step & 1;
    if (step + 1 < nsteps) stage(cur ^ 1, kbase + (step + 1) * BK);

    const int koff = (lane >> 4) << 3;
    const int rsel = lane & 15;
    short8 afr[8];
#pragma unroll
    for (int mf = 0; mf < 8; ++mf)
      afr[mf] = *(const short8*)&Alds[cur][wm * 128 + mf * 16 + rsel][koff];
    short8 bfr[4];
#pragma unroll
    for (int nf = 0; nf < 4; ++nf)
      bfr[nf] = *(const short8*)&Blds[cur][wn * 64 + nf * 16 + rsel][koff];
#pragma unroll
    for (int mf = 0; mf < 8; ++mf)
#pragma unroll
      for (int nf = 0; nf < 4; ++nf)
        acc[mf][nf] = __builtin_amdgcn_mfma_f32_16x16x32_bf16(
            __builtin_bit_cast(bf16x8, afr[mf]), __builtin_bit_cast(bf16x8, bfr[nf]),
            acc[mf][nf], 0, 0, 0);
    __syncthreads();
  }

  // epilogue: bf16 partial store. C/D layout: col=lane&15, row=(lane>>4)*4+j
  ushort* p = parts + (size_t)blockIdx.y * N_TOT * FEATS;
#pragma unroll
  for (int mf = 0; mf < 8; ++mf)
#pragma unroll
    for (int nf = 0; nf < 4; ++nf)
#pragma unroll
      for (int j = 0; j < 4; ++j) {
        const int row = wm * 128 + mf * 16 + ((lane >> 4) << 2) + j;
        const int col = wn * 64 + nf * 16 + (lane & 15);
        p[(m0 + row) * FEATS + col] = f2bf(acc[mf][nf][j]);
      }
}

// ---- K2: out = relu((sum_p parts[p]) @ W^T + b), MFMA over K2=256
// grid 256 blocks, 256 threads = 4 waves; wave computes 16 rows x 256 cols
__global__ __launch_bounds__(256) void k_gemm2(const ushort* __restrict__ parts,
                                               const ushort* __restrict__ Wb,
                                               const float* __restrict__ bias,
                                               float* __restrict__ out) {
  __shared__ ushort Al[64][264];   // 33 KiB, stride 528B = 33*16 -> 16B aligned
  __shared__ ushort Bl[FEATS][40]; // 20 KiB
  const int tid = threadIdx.x;
  const int lane = tid & 63, w = tid >> 6;
  const size_t m0 = (size_t)blockIdx.x * 64;

  // stage A = sum of KSPLIT partials (fp32 add, bf16 store)
  for (int c = tid; c < 2048; c += 256) {
    const int row = c >> 5;
    const int k8 = (c & 31) << 3;
    const size_t off = (m0 + row) * FEATS + k8;
    float s[8] = {0, 0, 0, 0, 0, 0, 0, 0};
#pragma unroll
    for (int p = 0; p < KSPLIT; ++p) {
      const short8 v = *(const short8*)(parts + (size_t)p * N_TOT * FEATS + off);
#pragma unroll
      for (int j = 0; j < 8; ++j) s[j] += bf2f((ushort)v[j]);
    }
    short8 ov;
#pragma unroll
    for (int j = 0; j < 8; ++j) ov[j] = (short)f2bf(s[j]);
    *(short8*)&Al[row][k8] = ov;
  }

  f32x4 acc[16] = {};
  for (int kk = 0; kk < FEATS; kk += 32) {
    __syncthreads();  // also covers A-staging before first use
#pragma unroll
    for (int q = 0; q < 4; ++q) {
      const short8 v = *(const short8*)(Wb + (size_t)tid * FEATS + kk + q * 8);
      *(short8*)&Bl[tid][q * 8] = v;
    }
    __syncthreads();
    const int koff = (lane >> 4) << 3;
    const short8 af = *(const short8*)&Al[w * 16 + (lane & 15)][kk + koff];
#pragma unroll
    for (int nf = 0; nf < 16; ++nf) {
      const short8 bfv = *(const short8*)&Bl[nf * 16 + (lane & 15)][koff];
      acc[nf] = __builtin_amdgcn_mfma_f32_16x16x32_bf16(
          __builtin_bit_cast(bf16x8, af), __builtin_bit_cast(bf16x8, bfv),
          acc[nf], 0, 0, 0);
    }
  }

#pragma unroll
  for (int nf = 0; nf < 16; ++nf) {
    const int col = nf * 16 + (lane & 15);
    const float bc = bias[col];
#pragma unroll
    for (int j = 0; j < 4; ++j) {
      const int row = w * 16 + ((lane >> 4) << 2) + j;
      const float v = acc[nf][j] + bc;
      out[(m0 + row) * FEATS + col] = fmaxf(v, 0.0f);
    }
  }
}

extern "C" void kernel_launch(void* const* d_in, const int* in_sizes, int n_in,
                              void* d_out, int out_size, void* d_ws, size_t ws_size,
                              hipStream_t stream) {
  const float* graph = (const float*)d_in[0];
  const float* feat  = (const float*)d_in[1];
  const float* W     = (const float*)d_in[2];
  const float* bias  = (const float*)d_in[3];
  float* out = (float*)d_out;

  char* ws = (char*)d_ws;
  ushort* fT    = (ushort*)ws;                                        // 8 MiB
  ushort* Wb    = (ushort*)(ws + (size_t)8 * 1024 * 1024);            // 128 KiB
  ushort* parts = (ushort*)(ws + (size_t)8 * 1024 * 1024 + 131072);   // 32 MiB

  k_transpose<<<dim3(N_TOT / 64, FEATS / 64), 256, 0, stream>>>(feat, fT);
  k_convw<<<dim3(64), 256, 0, stream>>>(W, Wb);
  k_gemm1<<<dim3(N_TOT / BM, KSPLIT), 512, 0, stream>>>(graph, fT, parts);
  k_gemm2<<<dim3(N_TOT / 64), 256, 0, stream>>>(parts, Wb, bias, out);
}

// Round 2
// 288.975 us; speedup vs baseline: 1.0394x; 1.0394x over previous
//
#include <hip/hip_runtime.h>
#include <hip/hip_bf16.h>

typedef float f32x4 __attribute__((ext_vector_type(4)));
typedef short short8 __attribute__((ext_vector_type(8)));
typedef __bf16 bf16x8 __attribute__((ext_vector_type(8)));

#define N_TOT 16384
#define FEATS 256
#define BM 256
#define BK 32
#define KSPLIT 4
#define LDA 40   // pad: 40 bf16 = 80B row stride, near-uniform banks, 16B aligned
#define NSTEPS ((N_TOT / KSPLIT) / BK)   // 128

static __device__ __forceinline__ ushort f2bf(float f) {
  union { __hip_bfloat16 b; ushort u; } cv;
  cv.b = __float2bfloat16(f);
  return cv.u;
}
static __device__ __forceinline__ float bf2f(ushort u) {
  union { unsigned int i; float f; } c;
  c.i = ((unsigned int)u) << 16;
  return c.f;
}

// ---- K0a: transpose+convert features [16384][256] f32 -> fT [256][16384] bf16
__global__ __launch_bounds__(256) void k_transpose(const float* __restrict__ feat,
                                                   ushort* __restrict__ fT) {
  __shared__ float tile[64][65];
  const int tx = threadIdx.x & 63, ty = threadIdx.x >> 6;
  const int k0 = blockIdx.x * 64, n0 = blockIdx.y * 64;
#pragma unroll
  for (int j = 0; j < 64; j += 4)
    tile[ty + j][tx] = feat[(size_t)(k0 + ty + j) * FEATS + n0 + tx];
  __syncthreads();
#pragma unroll
  for (int j = 0; j < 64; j += 4)
    fT[(size_t)(n0 + ty + j) * N_TOT + k0 + tx] = f2bf(tile[tx][ty + j]);
}

// ---- K0b: convert W [256][256] f32 -> bf16 ([o][i] kept: that IS B^T layout)
__global__ __launch_bounds__(256) void k_convw(const float* __restrict__ W,
                                               ushort* __restrict__ Wb) {
  int i = (blockIdx.x * 256 + threadIdx.x) * 4;
  float4 v = *(const float4*)(W + i);
  ushort4 h = { f2bf(v.x), f2bf(v.y), f2bf(v.z), f2bf(v.w) };
  *(ushort4*)(Wb + i) = h;
}

// ---- K1: parts[kb] = graph[:, kchunk] @ features[kchunk, :]   (bf16 MFMA)
// 512 thr = 8 waves (2M x 4N), wave tile 128x64, depth-2 async staging pipeline.
struct SRegs { float4 a[4]; uint4 b[2]; };

__global__ __launch_bounds__(512, 2) void k_gemm1(const float* __restrict__ graph,
                                                  const ushort* __restrict__ fT,
                                                  ushort* __restrict__ parts) {
  __shared__ ushort Alds[2][BM][LDA];     // 40 KiB
  __shared__ ushort Blds[2][FEATS][LDA];  // 40 KiB
  const int tid = threadIdx.x;
  const int lane = tid & 63, w = tid >> 6;
  const int wm = w >> 2, wn = w & 3;
  const size_t m0 = (size_t)blockIdx.x * BM;
  const int kbase = blockIdx.y * (N_TOT / KSPLIT);

  const float*  gA = graph + m0 * N_TOT + kbase;
  const ushort* gB = fT + kbase;

  f32x4 acc[8][4] = {};
  SRegs r0, r1;

  // issue global loads for K-tile t into regs (dense: each instr = contiguous 1KB/wave)
  auto issue = [&](SRegs& r, int t) {
    const float*  a = gA + t * BK;
    const ushort* b = gB + t * BK;
#pragma unroll
    for (int i = 0; i < 4; ++i) {
      const int f4 = i * 512 + tid;                 // flat float4 index in 256x32 tile
      r.a[i] = *(const float4*)(a + (size_t)(f4 >> 3) * N_TOT + (f4 & 7) * 4);
    }
#pragma unroll
    for (int i = 0; i < 2; ++i) {
      const int f16 = i * 512 + tid;                // flat 16B index in 256x32 bf16 tile
      r.b[i] = *(const uint4*)(b + (size_t)(f16 >> 2) * N_TOT + (f16 & 3) * 8);
    }
  };
  // convert + write regs into an LDS buffer (compiler emits counted vmcnt here)
  auto cwrite = [&](ushort (*Al)[LDA], ushort (*Bl)[LDA], SRegs& r) {
#pragma unroll
    for (int i = 0; i < 4; ++i) {
      const int f4 = i * 512 + tid;
      ushort4 h = { f2bf(r.a[i].x), f2bf(r.a[i].y), f2bf(r.a[i].z), f2bf(r.a[i].w) };
      *(ushort4*)&Al[f4 >> 3][(f4 & 7) * 4] = h;
    }
#pragma unroll
    for (int i = 0; i < 2; ++i) {
      const int f16 = i * 512 + tid;
      *(uint4*)&Bl[f16 >> 2][(f16 & 3) * 8] = r.b[i];
    }
  };

  // prologue: tile0 -> buf0; tile1 loads in flight in r1
  issue(r0, 0);
  issue(r1, 1);
  cwrite(Alds[0], Blds[0], r0);
  asm volatile("s_waitcnt lgkmcnt(0)" ::: "memory");
  __builtin_amdgcn_s_barrier();

  const int koff = (lane >> 4) << 3;
  const int rsel = lane & 15;

  // one K-tile: write tile t+1 (regs->LDS other buf), issue loads tile t+2,
  // compute tile t from current buf. Raw barriers: vmcnt never drained to 0.
  auto tile = [&](ushort (*Ac)[LDA], ushort (*Bc)[LDA],
                  ushort (*An)[LDA], ushort (*Bn)[LDA],
                  SRegs& rw, SRegs& ri, int t) {
    if (t + 1 < NSTEPS) cwrite(An, Bn, rw);     // consume rw (counted vmcnt wait)
    if (t + 2 < NSTEPS) issue(ri, t + 2);       // refill ri (stays in flight)
    __builtin_amdgcn_sched_barrier(0);          // pin load issue before compute
    short8 bfr[4];
#pragma unroll
    for (int nf = 0; nf < 4; ++nf)
      bfr[nf] = *(const short8*)&Bc[wn * 64 + nf * 16 + rsel][koff];
    asm volatile("s_waitcnt lgkmcnt(0)" ::: "memory");  // drain LDS writes pre-barrier
    __builtin_amdgcn_s_barrier();
    __builtin_amdgcn_s_setprio(1);
#pragma unroll
    for (int mf = 0; mf < 8; ++mf) {
      const short8 afr = *(const short8*)&Ac[wm * 128 + mf * 16 + rsel][koff];
#pragma unroll
      for (int nf = 0; nf < 4; ++nf)
        acc[mf][nf] = __builtin_amdgcn_mfma_f32_16x16x32_bf16(
            __builtin_bit_cast(bf16x8, afr), __builtin_bit_cast(bf16x8, bfr[nf]),
            acc[mf][nf], 0, 0, 0);
    }
    __builtin_amdgcn_s_setprio(0);
    asm volatile("s_waitcnt lgkmcnt(0)" ::: "memory");
    __builtin_amdgcn_s_barrier();               // reads of Ac done before next write
  };

  for (int t = 0; t < NSTEPS; t += 2) {         // NSTEPS even: both calls always run
    tile(Alds[0], Blds[0], Alds[1], Blds[1], r1, r0, t);
    tile(Alds[1], Blds[1], Alds[0], Blds[0], r0, r1, t + 1);
  }

  // epilogue: bf16 partial store. C/D: col=lane&15, row=(lane>>4)*4+j (verified r1)
  ushort* p = parts + (size_t)blockIdx.y * N_TOT * FEATS;
#pragma unroll
  for (int mf = 0; mf < 8; ++mf)
#pragma unroll
    for (int nf = 0; nf < 4; ++nf)
#pragma unroll
      for (int j = 0; j < 4; ++j) {
        const int row = wm * 128 + mf * 16 + ((lane >> 4) << 2) + j;
        const int col = wn * 64 + nf * 16 + (lane & 15);
        p[(m0 + row) * FEATS + col] = f2bf(acc[mf][nf][j]);
      }
}

// ---- K2: out = relu((sum_p parts[p]) @ W^T + b), MFMA over K2=256
__global__ __launch_bounds__(256) void k_gemm2(const ushort* __restrict__ parts,
                                               const ushort* __restrict__ Wb,
                                               const float* __restrict__ bias,
                                               float* __restrict__ out) {
  __shared__ ushort Al[64][264];   // stride 528B, 16B aligned
  __shared__ ushort Bl[FEATS][40];
  const int tid = threadIdx.x;
  const int lane = tid & 63, w = tid >> 6;
  const size_t m0 = (size_t)blockIdx.x * 64;

  for (int c = tid; c < 2048; c += 256) {
    const int row = c >> 5;
    const int k8 = (c & 31) << 3;
    const size_t off = (m0 + row) * FEATS + k8;
    float s[8] = {0, 0, 0, 0, 0, 0, 0, 0};
#pragma unroll
    for (int p = 0; p < KSPLIT; ++p) {
      const short8 v = *(const short8*)(parts + (size_t)p * N_TOT * FEATS + off);
#pragma unroll
      for (int j = 0; j < 8; ++j) s[j] += bf2f((ushort)v[j]);
    }
    short8 ov;
#pragma unroll
    for (int j = 0; j < 8; ++j) ov[j] = (short)f2bf(s[j]);
    *(short8*)&Al[row][k8] = ov;
  }

  f32x4 acc[16] = {};
  for (int kk = 0; kk < FEATS; kk += 32) {
    __syncthreads();
#pragma unroll
    for (int q = 0; q < 4; ++q) {
      const short8 v = *(const short8*)(Wb + (size_t)tid * FEATS + kk + q * 8);
      *(short8*)&Bl[tid][q * 8] = v;
    }
    __syncthreads();
    const int koff = (lane >> 4) << 3;
    const short8 af = *(const short8*)&Al[w * 16 + (lane & 15)][kk + koff];
#pragma unroll
    for (int nf = 0; nf < 16; ++nf) {
      const short8 bfv = *(const short8*)&Bl[nf * 16 + (lane & 15)][koff];
      acc[nf] = __builtin_amdgcn_mfma_f32_16x16x32_bf16(
          __builtin_bit_cast(bf16x8, af), __builtin_bit_cast(bf16x8, bfv),
          acc[nf], 0, 0, 0);
    }
  }

#pragma unroll
  for (int nf = 0; nf < 16; ++nf) {
    const int col = nf * 16 + (lane & 15);
    const float bc = bias[col];
#pragma unroll
    for (int j = 0; j < 4; ++j) {
      const int row = w * 16 + ((lane >> 4) << 2) + j;
      const float v = acc[nf][j] + bc;
      out[(m0 + row) * FEATS + col] = fmaxf(v, 0.0f);
    }
  }
}

extern "C" void kernel_launch(void* const* d_in, const int* in_sizes, int n_in,
                              void* d_out, int out_size, void* d_ws, size_t ws_size,
                              hipStream_t stream) {
  const float* graph = (const float*)d_in[0];
  const float* feat  = (const float*)d_in[1];
  const float* W     = (const float*)d_in[2];
  const float* bias  = (const float*)d_in[3];
  float* out = (float*)d_out;

  char* ws = (char*)d_ws;
  ushort* fT    = (ushort*)ws;                                        // 8 MiB
  ushort* Wb    = (ushort*)(ws + (size_t)8 * 1024 * 1024);            // 128 KiB
  ushort* parts = (ushort*)(ws + (size_t)8 * 1024 * 1024 + 131072);   // 32 MiB

  k_transpose<<<dim3(N_TOT / 64, FEATS / 64), 256, 0, stream>>>(feat, fT);
  k_convw<<<dim3(64), 256, 0, stream>>>(W, Wb);
  k_gemm1<<<dim3(N_TOT / BM, KSPLIT), 512, 0, stream>>>(graph, fT, parts);
  k_gemm2<<<dim3(N_TOT / 64), 256, 0, stream>>>(parts, Wb, bias, out);
}